// Round 1
// baseline (321.846 us; speedup 1.0000x reference)
//
#include <hip/hip_runtime.h>
#include <hip/hip_bf16.h>
#include <math.h>

// ---------------------------------------------------------------------------
// AdaHAN: conv(5x5)->avgpool(3x3,s2,pad1,/9)->relu x3 ; GRU(L=2048,H=8) ;
// 1x1 conv fuse ; top-2 presence mask ; sparse FC + log_softmax.
// Serial bottleneck = GRU recurrence; gi = W_ih x_t + b_ih precomputed in
// parallel, recurrent part runs on one wave with readlane h-broadcast.
// ---------------------------------------------------------------------------

static __device__ __forceinline__ float rcpf_(float x) {
    return __builtin_amdgcn_rcpf(x);
}
static __device__ __forceinline__ float bcast_lane(float v, int lane) {
    return __int_as_float(__builtin_amdgcn_readlane(__float_as_int(v), lane));
}

// ---------------- fused conv(5x5,pad2) + avgpool(3x3,s2,pad1)/9 + relu ------
template<int C_IN, int H_IN>
__global__ __launch_bounds__(256) void conv_pool_relu_k(
    const float* __restrict__ in, const float* __restrict__ w,
    const float* __restrict__ b, float* __restrict__ out)
{
    const int HO = H_IN / 2;
    int tid = blockIdx.x * 256 + threadIdx.x;
    if (tid >= 8 * HO * HO) return;
    int ox = tid & (HO - 1);
    int oy = (tid / HO) & (HO - 1);
    int c  = tid / (HO * HO);

    float acc[3][3];
#pragma unroll
    for (int a = 0; a < 3; ++a)
#pragma unroll
        for (int q = 0; q < 3; ++q) acc[a][q] = 0.f;

    const int iy0 = 2 * oy - 3, ix0 = 2 * ox - 3;

    for (int ci = 0; ci < C_IN; ++ci) {
        // 7x7 input tile covering the 9 conv pixels of this pool window
        float tile[7][7];
#pragma unroll
        for (int r = 0; r < 7; ++r) {
            int iy = iy0 + r;
            bool vy = (iy >= 0) && (iy < H_IN);
            const float* rowp = in + ((long long)ci * H_IN + iy) * H_IN;
#pragma unroll
            for (int cc = 0; cc < 7; ++cc) {
                int ix = ix0 + cc;
                bool v = vy && (ix >= 0) && (ix < H_IN);
                tile[r][cc] = v ? rowp[ix] : 0.f;
            }
        }
        const float* wp = w + (c * C_IN + ci) * 25;
        float wk[25];
#pragma unroll
        for (int q = 0; q < 25; ++q) wk[q] = wp[q];
#pragma unroll
        for (int py = 0; py < 3; ++py)
#pragma unroll
            for (int px = 0; px < 3; ++px) {
                float s = acc[py][px];
#pragma unroll
                for (int ky = 0; ky < 5; ++ky)
#pragma unroll
                    for (int kx = 0; kx < 5; ++kx)
                        s = fmaf(tile[py + ky][px + kx], wk[ky * 5 + kx], s);
                acc[py][px] = s;
            }
    }
    // pool: sum valid conv pixels (+bias each), pad counts as 0, divide by 9
    float bias = b[c];
    float sum = 0.f;
#pragma unroll
    for (int py = 0; py < 3; ++py) {
        int cy = 2 * oy - 1 + py;
        if (cy < 0 || cy >= H_IN) continue;
#pragma unroll
        for (int px = 0; px < 3; ++px) {
            int cx = 2 * ox - 1 + px;
            if (cx >= 0 && cx < H_IN) sum += acc[py][px] + bias;
        }
    }
    out[tid] = fmaxf(sum * (1.f / 9.f), 0.f);
}

// ---------------- gi[t,row] = b_ih[row] + W_ih[row,:] . emb[sent[t],:] ------
__global__ __launch_bounds__(256) void gi_k(
    const int* __restrict__ sent, const float* __restrict__ emb,
    const float* __restrict__ w_ih, const float* __restrict__ b_ih,
    float* __restrict__ gi)
{
    int tid = blockIdx.x * 256 + threadIdx.x;
    int t = tid >> 5, row = tid & 31;
    if (row >= 24) return;  // t < 2048 by grid size
    const float* x = emb + (long long)sent[t] * 8;
    const float* wr = w_ih + row * 8;
    float s = b_ih[row];
#pragma unroll
    for (int k = 0; k < 8; ++k) s = fmaf(wr[k], x[k], s);
    gi[t * 24 + row] = s;
}

// ---------------- serial GRU: 1 wave; lane j (mod 8) owns rows j,j+8,j+16 ---
__global__ __launch_bounds__(64) void gru_k(
    const float* __restrict__ gi, const float* __restrict__ w_hh,
    const float* __restrict__ b_hh, float* __restrict__ h_out)
{
    const int j = threadIdx.x & 7;
    float wr[8], wz[8], wn[8];
#pragma unroll
    for (int k = 0; k < 8; ++k) {
        wr[k] = w_hh[j * 8 + k];
        wz[k] = w_hh[(8 + j) * 8 + k];
        wn[k] = w_hh[(16 + j) * 8 + k];
    }
    const float br = b_hh[j], bz = b_hh[8 + j], bn = b_hh[16 + j];

    float h[8];
#pragma unroll
    for (int k = 0; k < 8; ++k) h[k] = 0.f;
    float hj = 0.f;  // this lane's own h[j]

    // depth-8 register prefetch of gi (L2/HBM latency >> step latency)
    float pr[8], pz[8], pn[8];
#pragma unroll
    for (int t = 0; t < 8; ++t) {
        const float* g = gi + t * 24;
        pr[t] = g[j]; pz[t] = g[8 + j]; pn[t] = g[16 + j];
    }

#pragma unroll 8   // makes (t & 7) indices compile-time -> stays in registers
    for (int t = 0; t < 2048; ++t) {
        const int s = t & 7;
        float gr = pr[s], gz = pz[s], gn = pn[s];
        int tp = t + 8; tp = tp > 2047 ? 2047 : tp;
        const float* gp = gi + tp * 24;
        pr[s] = gp[j]; pz[s] = gp[8 + j]; pn[s] = gp[16 + j];

        float dr = br, dz = bz, dn = bn;
#pragma unroll
        for (int k = 0; k < 8; ++k) {
            dr = fmaf(wr[k], h[k], dr);
            dz = fmaf(wz[k], h[k], dz);
            dn = fmaf(wn[k], h[k], dn);
        }
        float ar = gr + dr, az = gz + dz;
        float r = rcpf_(1.f + __expf(-ar));              // sigmoid
        float z = rcpf_(1.f + __expf(-az));              // sigmoid
        float nx = fmaf(r, dn, gn);
        float n = fmaf(-2.f, rcpf_(1.f + __expf(2.f * nx)), 1.f);  // tanh
        float hn = fmaf(z, hj - n, n);                   // (1-z)n + z h
        hj = hn;
#pragma unroll
        for (int k = 0; k < 8; ++k) h[k] = bcast_lane(hn, k);
    }
    if (threadIdx.x == 0) {
#pragma unroll
        for (int k = 0; k < 8; ++k) h_out[k] = h[k];
    }
}

// ---------------- fuse: +h, 1x1 conv, presence, top-2, mask ----------------
__global__ __launch_bounds__(1024) void fuse_k(
    const float* __restrict__ x3, const float* __restrict__ hv,
    const float* __restrict__ w1, const float* __restrict__ b1,
    float* __restrict__ mask_out, float* __restrict__ sm, int* __restrict__ si)
{
    __shared__ float pres[1024], mvec[1024], rv[1024];
    __shared__ int   ri[1024];
    __shared__ int   s_i1, s_i2;
    const int i = threadIdx.x;

    float e[8];
#pragma unroll
    for (int c = 0; c < 8; ++c) e[c] = x3[c * 1024 + i] + hv[c];
    float r0 = b1[0], r1 = b1[1];
#pragma unroll
    for (int c = 0; c < 8; ++c) {
        r0 = fmaf(w1[c], e[c], r0);
        r1 = fmaf(w1[8 + c], e[c], r1);
    }
    float p = r0 * r0 + r1 * r1;
    pres[i] = p; mvec[i] = r0 + r1;
    rv[i] = p; ri[i] = i;
    __syncthreads();
    for (int s = 512; s > 0; s >>= 1) {
        if (i < s) {
            float ov = rv[i + s]; int oi = ri[i + s];
            if (ov > rv[i] || (ov == rv[i] && oi < ri[i])) { rv[i] = ov; ri[i] = oi; }
        }
        __syncthreads();
    }
    if (i == 0) s_i1 = ri[0];
    __syncthreads();
    const int i1 = s_i1;
    rv[i] = (i == i1) ? -__builtin_inff() : pres[i];
    ri[i] = i;
    __syncthreads();
    for (int s = 512; s > 0; s >>= 1) {
        if (i < s) {
            float ov = rv[i + s]; int oi = ri[i + s];
            if (ov > rv[i] || (ov == rv[i] && oi < ri[i])) { rv[i] = ov; ri[i] = oi; }
        }
        __syncthreads();
    }
    if (i == 0) s_i2 = ri[0];
    __syncthreads();
    const int i2 = s_i2;
    mask_out[i] = (i == i1 || i == i2) ? 1.f : 0.f;
    if (i == 0) {
        sm[0] = mvec[i1]; sm[1] = mvec[i2];
        si[0] = i1;       si[1] = i2;
    }
}

// ---------------- sparse FC (K=2 cols) + log_softmax over 1000 -------------
__global__ __launch_bounds__(1024) void fc_k(
    const float* __restrict__ W, const float* __restrict__ bias,
    const float* __restrict__ sm, const int* __restrict__ si,
    float* __restrict__ out)
{
    __shared__ float buf[1024];
    __shared__ float s_max, s_lse;
    const int c = threadIdx.x;
    const int i1 = si[0], i2 = si[1];
    const float a1 = sm[0], a2 = sm[1];

    float lg = -__builtin_inff();
    if (c < 1000)
        lg = bias[c] + a1 * W[(long long)c * 1024 + i1]
                     + a2 * W[(long long)c * 1024 + i2];
    buf[c] = lg;
    __syncthreads();
    for (int s = 512; s > 0; s >>= 1) {
        if (c < s) buf[c] = fmaxf(buf[c], buf[c + s]);
        __syncthreads();
    }
    if (c == 0) s_max = buf[0];
    __syncthreads();
    const float m = s_max;
    buf[c] = (c < 1000) ? __expf(lg - m) : 0.f;
    __syncthreads();
    for (int s = 512; s > 0; s >>= 1) {
        if (c < s) buf[c] += buf[c + s];
        __syncthreads();
    }
    if (c == 0) s_lse = logf(buf[0]);
    __syncthreads();
    if (c < 1000) out[c] = lg - m - s_lse;
}

// ---------------------------------------------------------------------------
extern "C" void kernel_launch(void* const* d_in, const int* in_sizes, int n_in,
                              void* d_out, int out_size, void* d_ws, size_t ws_size,
                              hipStream_t stream)
{
    const float* image = (const float*)d_in[0];
    const int*   sent  = (const int*)  d_in[1];
    const float* c1w = (const float*)d_in[2];
    const float* c1b = (const float*)d_in[3];
    const float* c2w = (const float*)d_in[4];
    const float* c2b = (const float*)d_in[5];
    const float* c3w = (const float*)d_in[6];
    const float* c3b = (const float*)d_in[7];
    const float* emb = (const float*)d_in[8];
    const float* wih = (const float*)d_in[9];
    const float* whh = (const float*)d_in[10];
    const float* bih = (const float*)d_in[11];
    const float* bhh = (const float*)d_in[12];
    const float* w1  = (const float*)d_in[13];
    const float* b1  = (const float*)d_in[14];
    const float* fcw = (const float*)d_in[15];
    const float* fcb = (const float*)d_in[16];
    float* out = (float*)d_out;

    char* ws = (char*)d_ws;
    float* x1 = (float*)(ws);                                  // 8*128*128 f32
    float* x2 = (float*)(ws + 262144);                         // 8*64*64
    float* x3 = (float*)(ws + 262144 + 131072);                // 8*32*32
    float* gi = (float*)(ws + 262144 + 131072 + 32768);        // 2048*24
    float* hv = (float*)(ws + 262144 + 131072 + 32768 + 196608); // 8
    float* sm = hv + 8;                                        // 2
    int*   si = (int*)(sm + 2);                                // 2

    conv_pool_relu_k<3, 256><<<512, 256, 0, stream>>>(image, c1w, c1b, x1);
    conv_pool_relu_k<8, 128><<<128, 256, 0, stream>>>(x1, c2w, c2b, x2);
    conv_pool_relu_k<8, 64><<<32, 256, 0, stream>>>(x2, c3w, c3b, x3);
    gi_k<<<256, 256, 0, stream>>>(sent, emb, wih, bih, gi);
    gru_k<<<1, 64, 0, stream>>>(gi, whh, bhh, hv);
    fuse_k<<<1, 1024, 0, stream>>>(x3, hv, w1, b1, out + 1000, sm, si);
    fc_k<<<1, 1024, 0, stream>>>(fcw, fcb, sm, si, out);
}

// Round 2
// 249.814 us; speedup vs baseline: 1.2883x; 1.2883x over previous
//
#include <hip/hip_runtime.h>
#include <hip/hip_bf16.h>
#include <math.h>

// ---------------------------------------------------------------------------
// AdaHAN: conv(5x5)->avgpool(3x3,s2,pad1,/9)->relu x3 ; GRU(L=2048,H=8) ;
// 1x1 conv fuse ; top-2 presence mask ; sparse FC + log_softmax.
// GRU is the serial bottleneck: lane 4j+s layout, DPP quad_perm gate
// exchange, exp2-domain prescaling, 1 prefetched load/step.
// ---------------------------------------------------------------------------

#define C_SIG  (-1.44269504088896340736f)   // -log2(e)
#define C_TANH ( 2.88539008177792681472f)   // 2*log2(e)

static __device__ __forceinline__ float rcpf_(float x) {
    return __builtin_amdgcn_rcpf(x);
}
static __device__ __forceinline__ float bcast_lane(float v, int lane) {
    return __int_as_float(__builtin_amdgcn_readlane(__float_as_int(v), lane));
}
template<int SEL>  // broadcast lane SEL of each quad to the whole quad
static __device__ __forceinline__ float dpp_bcast(float v) {
    return __int_as_float(__builtin_amdgcn_update_dpp(
        0, __float_as_int(v), SEL * 0x55, 0xF, 0xF, true));
}

// ---------------- fused conv(5x5,pad2) + avgpool(3x3,s2,pad1)/9 + relu ------
template<int C_IN, int H_IN>
__global__ __launch_bounds__(256) void conv_pool_relu_k(
    const float* __restrict__ in, const float* __restrict__ w,
    const float* __restrict__ b, float* __restrict__ out)
{
    const int HO = H_IN / 2;
    int tid = blockIdx.x * 256 + threadIdx.x;
    if (tid >= 8 * HO * HO) return;
    int ox = tid & (HO - 1);
    int oy = (tid / HO) & (HO - 1);
    int c  = tid / (HO * HO);

    float acc[3][3];
#pragma unroll
    for (int a = 0; a < 3; ++a)
#pragma unroll
        for (int q = 0; q < 3; ++q) acc[a][q] = 0.f;

    const int iy0 = 2 * oy - 3, ix0 = 2 * ox - 3;

    for (int ci = 0; ci < C_IN; ++ci) {
        float tile[7][7];
#pragma unroll
        for (int r = 0; r < 7; ++r) {
            int iy = iy0 + r;
            bool vy = (iy >= 0) && (iy < H_IN);
            const float* rowp = in + ((long long)ci * H_IN + iy) * H_IN;
#pragma unroll
            for (int cc = 0; cc < 7; ++cc) {
                int ix = ix0 + cc;
                bool v = vy && (ix >= 0) && (ix < H_IN);
                tile[r][cc] = v ? rowp[ix] : 0.f;
            }
        }
        const float* wp = w + (c * C_IN + ci) * 25;
        float wk[25];
#pragma unroll
        for (int q = 0; q < 25; ++q) wk[q] = wp[q];
#pragma unroll
        for (int py = 0; py < 3; ++py)
#pragma unroll
            for (int px = 0; px < 3; ++px) {
                float s = acc[py][px];
#pragma unroll
                for (int ky = 0; ky < 5; ++ky)
#pragma unroll
                    for (int kx = 0; kx < 5; ++kx)
                        s = fmaf(tile[py + ky][px + kx], wk[ky * 5 + kx], s);
                acc[py][px] = s;
            }
    }
    float bias = b[c];
    float sum = 0.f;
#pragma unroll
    for (int py = 0; py < 3; ++py) {
        int cy = 2 * oy - 1 + py;
        if (cy < 0 || cy >= H_IN) continue;
#pragma unroll
        for (int px = 0; px < 3; ++px) {
            int cx = 2 * ox - 1 + px;
            if (cx >= 0 && cx < H_IN) sum += acc[py][px] + bias;
        }
    }
    out[tid] = fmaxf(sum * (1.f / 9.f), 0.f);
}

// ---------------- gi'[t][32]: prescaled, bias-folded gate inputs ------------
// lane L=4j+s of step t:
//  s=0: C_SIG *(b_ih[j]    + b_hh[j]    + Wih[j]   .x)
//  s=1: C_SIG *(b_ih[8+j]  + b_hh[8+j]  + Wih[8+j] .x)
//  s=2: C_TANH* b_hh[16+j]                       (gh_n dot init)
//  s=3: C_TANH*(b_ih[16+j] +              Wih[16+j].x)  (gi_n carrier)
__global__ __launch_bounds__(256) void gi_k(
    const int* __restrict__ sent, const float* __restrict__ emb,
    const float* __restrict__ w_ih, const float* __restrict__ b_ih,
    const float* __restrict__ b_hh, float* __restrict__ gi)
{
    int tid = blockIdx.x * 256 + threadIdx.x;   // 65536 = 2048*32
    int t = tid >> 5, L = tid & 31;
    int j = L >> 2, s = L & 3;
    float val;
    if (s == 2) {
        val = C_TANH * b_hh[16 + j];
    } else {
        int row = (s == 0) ? j : (s == 1) ? 8 + j : 16 + j;
        const float* x = emb + (long long)sent[t] * 8;
        const float* wr = w_ih + row * 8;
        float acc = b_ih[row] + (s == 3 ? 0.f : b_hh[row]);
#pragma unroll
        for (int k = 0; k < 8; ++k) acc = fmaf(wr[k], x[k], acc);
        val = ((s < 2) ? C_SIG : C_TANH) * acc;
    }
    gi[t * 32 + L] = val;
}

// ---------------- serial GRU: 1 wave, lane 4j+s owns gate j / role s --------
__global__ __launch_bounds__(64) void gru_k(
    const float* __restrict__ gi, const float* __restrict__ w_hh,
    float* __restrict__ h_out)
{
    const int L = threadIdx.x & 31;
    const int j = L >> 2, s = L & 3;
    const int row = (s == 0) ? j : (s == 1) ? 8 + j : 16 + j;
    const float scale = (s < 2) ? C_SIG : C_TANH;
    float w[8];
#pragma unroll
    for (int k = 0; k < 8; ++k) w[k] = w_hh[row * 8 + k] * scale;

    float h0 = 0, h1 = 0, h2 = 0, h3 = 0, h4 = 0, h5 = 0, h6 = 0, h7 = 0;
    float hq = 0;   // this quad's h[j]

    float pr[8];    // depth-8 prefetch ring (static-indexed via unroll 8)
#pragma unroll
    for (int i = 0; i < 8; ++i) pr[i] = gi[i * 32 + L];

#pragma unroll 8
    for (int t = 0; t < 2048; ++t) {
        const int sl = t & 7;
        const float g = pr[sl];
        pr[sl] = gi[(t + 8) * 32 + L];  // t+8<=2055: junk-but-deterministic tail

        // dot(w, h) + g  as two 4-deep fma chains
        float a0 = fmaf(w[0], h0, g);
        a0 = fmaf(w[1], h1, a0);
        a0 = fmaf(w[2], h2, a0);
        a0 = fmaf(w[3], h3, a0);
        float a1 = w[4] * h4;
        a1 = fmaf(w[5], h5, a1);
        a1 = fmaf(w[6], h6, a1);
        a1 = fmaf(w[7], h7, a1);
        const float x = a0 + a1;   // s=0: -log2e*x_r ; s=1: -log2e*x_z ; s=2: 2log2e*gh_n

        const float sig = rcpf_(1.f + __builtin_amdgcn_exp2f(x)); // s=0:r, s=1:z
        const float r_b  = dpp_bcast<0>(sig);
        const float gn_b = dpp_bcast<3>(g);          // 2log2e*gi_n (off-path)
        const float y = fmaf(r_b, x, gn_b);          // lane s=2: 2log2e*(gi_n + r*gh_n)
        const float q = rcpf_(1.f + __builtin_amdgcn_exp2f(y)); // 1/(1+e^{2v}); tanh=1-2q
        const float z_b = dpp_bcast<1>(sig);
        const float omz = 1.f - z_b;                 // off-path (z ready early)
        const float ozh = fmaf(z_b, hq, omz);        // (1-z) + z*h
        const float m2o = -2.f * omz;
        const float q_b = dpp_bcast<2>(q);
        const float hn = fmaf(m2o, q_b, ozh);        // (1-z)(1-2q) + z*h
        hq = hn;
        h0 = bcast_lane(hn, 0);  h1 = bcast_lane(hn, 4);
        h2 = bcast_lane(hn, 8);  h3 = bcast_lane(hn, 12);
        h4 = bcast_lane(hn, 16); h5 = bcast_lane(hn, 20);
        h6 = bcast_lane(hn, 24); h7 = bcast_lane(hn, 28);
    }
    if (threadIdx.x == 0) {
        h_out[0] = h0; h_out[1] = h1; h_out[2] = h2; h_out[3] = h3;
        h_out[4] = h4; h_out[5] = h5; h_out[6] = h6; h_out[7] = h7;
    }
}

// ------- fuse (+h, 1x1 conv, presence, top-2, mask) THEN sparse FC+logsm ----
__global__ __launch_bounds__(1024) void fuse_fc_k(
    const float* __restrict__ x3, const float* __restrict__ hv,
    const float* __restrict__ w1, const float* __restrict__ b1,
    const float* __restrict__ W, const float* __restrict__ bias,
    float* __restrict__ out)   // out[0..999]=log_softmax, out[1000..2023]=mask
{
    __shared__ float pres[1024], mvec[1024], rv[1024];
    __shared__ int   ri[1024];
    __shared__ int   s_i1, s_i2;
    __shared__ float s_a1, s_a2, s_max, s_lse;
    const int i = threadIdx.x;

    float e[8];
#pragma unroll
    for (int c = 0; c < 8; ++c) e[c] = x3[c * 1024 + i] + hv[c];
    float r0 = b1[0], r1 = b1[1];
#pragma unroll
    for (int c = 0; c < 8; ++c) {
        r0 = fmaf(w1[c], e[c], r0);
        r1 = fmaf(w1[8 + c], e[c], r1);
    }
    float p = r0 * r0 + r1 * r1;
    pres[i] = p; mvec[i] = r0 + r1;
    rv[i] = p; ri[i] = i;
    __syncthreads();
    for (int s = 512; s > 0; s >>= 1) {
        if (i < s) {
            float ov = rv[i + s]; int oi = ri[i + s];
            if (ov > rv[i] || (ov == rv[i] && oi < ri[i])) { rv[i] = ov; ri[i] = oi; }
        }
        __syncthreads();
    }
    if (i == 0) s_i1 = ri[0];
    __syncthreads();
    const int i1 = s_i1;
    rv[i] = (i == i1) ? -__builtin_inff() : pres[i];
    ri[i] = i;
    __syncthreads();
    for (int s = 512; s > 0; s >>= 1) {
        if (i < s) {
            float ov = rv[i + s]; int oi = ri[i + s];
            if (ov > rv[i] || (ov == rv[i] && oi < ri[i])) { rv[i] = ov; ri[i] = oi; }
        }
        __syncthreads();
    }
    if (i == 0) {
        s_i2 = ri[0];
        s_a1 = mvec[i1]; s_a2 = mvec[ri[0]];
    }
    __syncthreads();
    const int i2 = s_i2;
    out[1000 + i] = (i == i1 || i == i2) ? 1.f : 0.f;

    // ---- sparse FC + log_softmax over 1000 classes ----
    const float a1 = s_a1, a2 = s_a2;
    float lg = -__builtin_inff();
    if (i < 1000)
        lg = bias[i] + a1 * W[(long long)i * 1024 + i1]
                     + a2 * W[(long long)i * 1024 + i2];
    rv[i] = lg;
    __syncthreads();
    for (int s = 512; s > 0; s >>= 1) {
        if (i < s) rv[i] = fmaxf(rv[i], rv[i + s]);
        __syncthreads();
    }
    if (i == 0) s_max = rv[0];
    __syncthreads();
    const float m = s_max;
    rv[i] = (i < 1000) ? __expf(lg - m) : 0.f;
    __syncthreads();
    for (int s = 512; s > 0; s >>= 1) {
        if (i < s) rv[i] += rv[i + s];
        __syncthreads();
    }
    if (i == 0) s_lse = logf(rv[0]);
    __syncthreads();
    if (i < 1000) out[i] = lg - m - s_lse;
}

// ---------------------------------------------------------------------------
extern "C" void kernel_launch(void* const* d_in, const int* in_sizes, int n_in,
                              void* d_out, int out_size, void* d_ws, size_t ws_size,
                              hipStream_t stream)
{
    const float* image = (const float*)d_in[0];
    const int*   sent  = (const int*)  d_in[1];
    const float* c1w = (const float*)d_in[2];
    const float* c1b = (const float*)d_in[3];
    const float* c2w = (const float*)d_in[4];
    const float* c2b = (const float*)d_in[5];
    const float* c3w = (const float*)d_in[6];
    const float* c3b = (const float*)d_in[7];
    const float* emb = (const float*)d_in[8];
    const float* wih = (const float*)d_in[9];
    const float* whh = (const float*)d_in[10];
    const float* bih = (const float*)d_in[11];
    const float* bhh = (const float*)d_in[12];
    const float* w1  = (const float*)d_in[13];
    const float* b1  = (const float*)d_in[14];
    const float* fcw = (const float*)d_in[15];
    const float* fcb = (const float*)d_in[16];
    float* out = (float*)d_out;

    char* ws = (char*)d_ws;
    // gi (2056*32 f32 = 263168 B) aliases x1 (+1KB of x2): both dead when
    // gi_k runs (stream order: conv1,conv2,conv3,gi,gru,fuse_fc).
    float* gi = (float*)(ws);
    float* x1 = (float*)(ws);                      // 8*128*128 f32 = 262144 B
    float* x2 = (float*)(ws + 262144);             // 8*64*64   f32 = 131072 B
    float* x3 = (float*)(ws + 262144 + 131072);    // 8*32*32   f32 =  32768 B
    float* hv = (float*)(ws + 262144 + 131072 + 32768);   // 8 f32

    conv_pool_relu_k<3, 256><<<512, 256, 0, stream>>>(image, c1w, c1b, x1);
    conv_pool_relu_k<8, 128><<<128, 256, 0, stream>>>(x1, c2w, c2b, x2);
    conv_pool_relu_k<8, 64><<<32, 256, 0, stream>>>(x2, c3w, c3b, x3);
    gi_k<<<256, 256, 0, stream>>>(sent, emb, wih, bih, bhh, gi);
    gru_k<<<1, 64, 0, stream>>>(gi, whh, hv);
    fuse_fc_k<<<1, 1024, 0, stream>>>(x3, hv, w1, b1, fcw, fcb, out);
}